// Round 10
// baseline (259.414 us; speedup 1.0000x reference)
//
#include <hip/hip_runtime.h>
#include <hip/hip_bf16.h>

#define B_  8
#define T_  2048
#define E_  1024
#define H_  64
#define BT_ (B_*T_)
#define NBLK 256

typedef __attribute__((ext_vector_type(8))) __bf16 bf16x8;
typedef __attribute__((ext_vector_type(4))) float  f32x4;

__device__ __forceinline__ unsigned short f2bfu(float f) {
    union { float f; unsigned u; } v; v.f = f;
    unsigned r = v.u + 0x7fffu + ((v.u >> 16) & 1u);
    return (unsigned short)(r >> 16);
}

__device__ __forceinline__ unsigned pk2(float lo, float hi) {
    __hip_bfloat162 h = __float22bfloat162_rn(float2{lo, hi});
    union { __hip_bfloat162 h; unsigned u; } v; v.h = h;
    return v.u;
}

#if defined(__has_builtin)
#if __has_builtin(__builtin_amdgcn_global_load_lds)
#define HAVE_GLL 1
#endif
#endif
__device__ __forceinline__ void dma16(const void* g, void* lds_base, int lane) {
#ifdef HAVE_GLL
    __builtin_amdgcn_global_load_lds(
        (const __attribute__((address_space(1))) unsigned*)(unsigned long long)g,
        (__attribute__((address_space(3))) unsigned*)(unsigned)(unsigned long long)lds_base,
        16, 0, 0);
#else
    *(uint4*)((char*)lds_base + lane * 16) = *(const uint4*)g;
#endif
}

// device-scope grid barrier: all NBLK blocks guaranteed co-resident (1/CU).
// Same construction as HIP cooperative groups grid.sync(): release fence +
// agent-scope atomic arrive, acquire-spin, acquire fence (cross-XCD wb/inv).
__device__ __forceinline__ void gridbar(unsigned* cnt, unsigned expected) {
    __syncthreads();
    if (threadIdx.x == 0) {
        __threadfence();
        __hip_atomic_fetch_add(cnt, 1u, __ATOMIC_RELEASE, __HIP_MEMORY_SCOPE_AGENT);
        while (__hip_atomic_load(cnt, __ATOMIC_ACQUIRE, __HIP_MEMORY_SCOPE_AGENT) < expected)
            __builtin_amdgcn_s_sleep(2);
        __threadfence();
    }
    __syncthreads();
}

#define QSCALE (0.125f * 1.44269504f)
#define WF_CHUNK_BYTES 12288
#define PSS 72

// ============ fused wprep + qkv + attn, own grid barrier ============
// 256 blocks x 512 threads (8 waves), LDS 35 KB phase-overlaid arena.
__global__ __launch_bounds__(512, 2)
void fused_kernel(const float* __restrict__ x,
                  const float* __restrict__ Wq,
                  const float* __restrict__ Wk,
                  const float* __restrict__ Wv,
                  unsigned short* __restrict__ qb,
                  unsigned short* __restrict__ kb,
                  unsigned short* __restrict__ vtb,
                  unsigned short* __restrict__ wf,
                  float* __restrict__ out,
                  unsigned* __restrict__ bar)
{
    __shared__ __align__(16) char smem[35840];
    const int tid = threadIdx.x;

    // ---------------- Phase 0: wprep ----------------
    // wf layout: [c(32)][m(3)][n(4)][lane(64)][j(8)] bf16; chunk = 12 KB.
    {
        const int t = blockIdx.x * 512 + tid;
        if (t < 96 * 256) {
            const int vb = t >> 8;
            const int vt = t & 255;
            const int c = vb / 3;
            const int m = vb % 3;
            const float* W = (m == 0) ? Wq : (m == 1 ? Wk : Wv);
            const float scale = (m == 0) ? QSCALE : 1.0f;
            const int n    = vt >> 6;
            const int lane = vt & 63;
            const int quad = lane >> 4;
            const int col  = lane & 15;
            const int h    = n * 16 + col;
            unsigned short tmp[8];
#pragma unroll
            for (int j = 0; j < 8; ++j)
                tmp[j] = f2bfu(W[(c * 32 + quad * 8 + j) * H_ + h] * scale);
            *(uint4*)&wf[(((c * 3 + m) * 4 + n) * 64 + lane) * 8] = *(uint4*)tmp;
        }
    }
    gridbar(&bar[0], NBLK);

    // ---------------- Phase 1: qkv ----------------
    // 2 passes x 2 arenas (16 tokens each); wf LDS double-buffer SHARED by
    // both arenas (12 KB/chunk, streamed once per 32 tokens). x fp32
    // XOR-swizzle DMA per arena (R8-verified).
    {
        char*  wfs = smem;                          // [2][12288]
        float* xsb = (float*)(smem + 24576);        // [2 arenas][2 bufs][512]
        const int w8   = tid >> 6;                  // 0..7
        const int a    = w8 >> 2;                   // arena
        const int wa   = w8 & 3;                    // wave-in-arena = h-tile
        const int lane = tid & 63;
        const int quad = lane >> 4;
        const int col  = lane & 15;
        const char* wfb = (const char*)wf;
        const int s0 = (2 * quad) ^ (col & 7);
        const int s1 = s0 ^ 1;
        float* xs = xsb + a * 1024;

        for (int pass = 0; pass < 2; ++pass) {
            const long r0 = ((long)blockIdx.x * 2 + a + pass * 512) * 16;
            const float* xg = x + (r0 + wa * 8 + (lane >> 3)) * E_
                                + (((lane & 7) ^ (lane >> 3)) * 4);

            f32x4 acc[3];
#pragma unroll
            for (int m = 0; m < 3; ++m) acc[m] = (f32x4){0.f, 0.f, 0.f, 0.f};

            // prologue: chunk 0 into buf 0 (12 wf slots: all waves L=w8, waves<4 also L=8+w8)
            dma16(wfb + w8 * 1024 + lane * 16, &wfs[w8 * 1024], lane);
            if (w8 < 4)
                dma16(wfb + (8 + w8) * 1024 + lane * 16, &wfs[(8 + w8) * 1024], lane);
            if (wa < 2) dma16(xg, &xs[wa * 256], lane);

            for (int c = 0; c < 32; ++c) {
                const int buf = c & 1;
                __syncthreads();                  // drains own DMAs (vmcnt) for all waves

                if (c + 1 < 32) {
                    const char* src = wfb + (long)(c + 1) * WF_CHUNK_BYTES;
                    char* dst = &wfs[(buf ^ 1) * 12288];
                    dma16(src + w8 * 1024 + lane * 16, dst + w8 * 1024, lane);
                    if (w8 < 4)
                        dma16(src + (8 + w8) * 1024 + lane * 16, dst + (8 + w8) * 1024, lane);
                    if (wa < 2) dma16(xg + (c + 1) * 32, &xs[(buf ^ 1) * 512 + wa * 256], lane);
                }

                float4 f0 = *(const float4*)&xs[buf * 512 + col * 32 + s0 * 4];
                float4 f1 = *(const float4*)&xs[buf * 512 + col * 32 + s1 * 4];
                unsigned pk[4];
                pk[0] = pk2(f0.x, f0.y);
                pk[1] = pk2(f0.z, f0.w);
                pk[2] = pk2(f1.x, f1.y);
                pk[3] = pk2(f1.z, f1.w);
                bf16x8 af = *(bf16x8*)pk;

#pragma unroll
                for (int m = 0; m < 3; ++m) {
                    bf16x8 bm = *(const bf16x8*)&wfs[buf * 12288 + m * 4096 + wa * 1024 + lane * 16];
                    acc[m] = __builtin_amdgcn_mfma_f32_16x16x32_bf16(af, bm, acc[m], 0, 0, 0);
                }
            }

            const int bidx = (int)(r0 >> 11);
            const int h    = wa * 16 + col;
#pragma unroll
            for (int r = 0; r < 4; ++r) {
                long t = r0 + quad * 4 + r;
                qb[t * H_ + h] = f2bfu(acc[0][r]);        // scale folded into Wq
                kb[t * H_ + h] = f2bfu(acc[1][r]);
                vtb[((long)(bidx * H_ + h)) * T_ + (t & (T_ - 1))] = f2bfu(acc[2][r]);
            }
            // pass boundary: next prologue writes buf0; last readers used buf1 — disjoint
        }
    }
    gridbar(&bar[1], NBLK);

    // ---------------- Phase 2: split-K flash attention (R8 body) ----------
    {
        unsigned short* ps = (unsigned short*)smem;        // [8][16*PSS]
        float* oc = (float*)smem;                          // [8][16][68]
        float* ml = (float*)(smem + 8 * 16 * 68 * 4);      // [8][2][16]

        const int g    = tid >> 6;
        const int lane = tid & 63;
        const int quad = lane >> 4;
        const int col  = lane & 15;

        for (int u = 0; u < 2; ++u) {
            const int unit = blockIdx.x + u * NBLK;        // 0..511
            const int b = unit & 7;
            const int p = unit >> 3;                       // 0..63

            const unsigned short* qbb = qb  + (long)b * T_ * H_;
            const unsigned short* kbb = kb  + (long)b * T_ * H_;
            const unsigned short* vbb = vtb + (long)b * H_ * T_;

            for (int half = 0; half < 2; ++half) {
                const int qt = half ? (127 - p) : p;
                const int nt = (qt + 4) >> 2;

                bf16x8 qa0 = *(const bf16x8*)&qbb[(qt * 16 + col) * H_ + quad * 8];
                bf16x8 qa1 = *(const bf16x8*)&qbb[(qt * 16 + col) * H_ + 32 + quad * 8];

                f32x4 o[4];
                float m_i[4], l_i[4];
#pragma unroll
                for (int n = 0; n < 4; ++n) o[n] = (f32x4){0.f, 0.f, 0.f, 0.f};
#pragma unroll
                for (int r = 0; r < 4; ++r) { m_i[r] = -1e30f; l_i[r] = 0.f; }

                bf16x8 kf[8];
                if (g < nt) {
#pragma unroll
                    for (int kt = 0; kt < 4; ++kt) {
                        const unsigned short* kp = kbb + ((long)(g * 64 + kt * 16 + col)) * H_ + quad * 8;
                        kf[kt * 2]     = *(const bf16x8*)kp;
                        kf[kt * 2 + 1] = *(const bf16x8*)(kp + 32);
                    }
                }

                for (int s = g; s < nt; s += 8) {
                    f32x4 sa[4];
#pragma unroll
                    for (int kt = 0; kt < 4; ++kt) {
                        sa[kt] = (f32x4){0.f, 0.f, 0.f, 0.f};
                        sa[kt] = __builtin_amdgcn_mfma_f32_16x16x32_bf16(qa0, kf[kt * 2],     sa[kt], 0, 0, 0);
                        sa[kt] = __builtin_amdgcn_mfma_f32_16x16x32_bf16(qa1, kf[kt * 2 + 1], sa[kt], 0, 0, 0);
                    }

                    bf16x8 vf[8];
#pragma unroll
                    for (int n = 0; n < 4; ++n) {
                        const unsigned short* vp = vbb + ((long)(n * 16 + col)) * T_ + s * 64 + quad * 8;
                        vf[n * 2]     = *(const bf16x8*)vp;
                        vf[n * 2 + 1] = *(const bf16x8*)(vp + 32);
                    }

                    if (s + 8 < nt) {
#pragma unroll
                        for (int kt = 0; kt < 4; ++kt) {
                            const unsigned short* kp = kbb + ((long)((s + 8) * 64 + kt * 16 + col)) * H_ + quad * 8;
                            kf[kt * 2]     = *(const bf16x8*)kp;
                            kf[kt * 2 + 1] = *(const bf16x8*)(kp + 32);
                        }
                    }

                    if (s == nt - 1) {
#pragma unroll
                        for (int kt = 0; kt < 4; ++kt) {
                            int kg = s * 64 + kt * 16 + col;
#pragma unroll
                            for (int r = 0; r < 4; ++r) {
                                int qg = qt * 16 + quad * 4 + r;
                                if (kg > qg) sa[kt][r] = -1e30f;
                            }
                        }
                    }

                    float mx[4];
#pragma unroll
                    for (int r = 0; r < 4; ++r)
                        mx[r] = fmaxf(fmaxf(sa[0][r], sa[1][r]), fmaxf(sa[2][r], sa[3][r]));
#pragma unroll
                    for (int off = 1; off < 16; off <<= 1)
#pragma unroll
                        for (int r = 0; r < 4; ++r)
                            mx[r] = fmaxf(mx[r], __shfl_xor(mx[r], off, 64));

                    float alpha[4], mnew[4];
#pragma unroll
                    for (int r = 0; r < 4; ++r) {
                        mnew[r]  = fmaxf(m_i[r], mx[r]);
                        alpha[r] = __builtin_amdgcn_exp2f(m_i[r] - mnew[r]);
                        m_i[r]   = mnew[r];
                    }

                    float rs[4] = {0.f, 0.f, 0.f, 0.f};
#pragma unroll
                    for (int kt = 0; kt < 4; ++kt)
#pragma unroll
                        for (int r = 0; r < 4; ++r) {
                            float pv = __builtin_amdgcn_exp2f(sa[kt][r] - mnew[r]);
                            rs[r] += pv;
                            ps[g * 16 * PSS + (quad * 4 + r) * PSS + kt * 16 + col] = f2bfu(pv);
                        }
#pragma unroll
                    for (int off = 1; off < 16; off <<= 1)
#pragma unroll
                        for (int r = 0; r < 4; ++r)
                            rs[r] += __shfl_xor(rs[r], off, 64);
#pragma unroll
                    for (int r = 0; r < 4; ++r)
                        l_i[r] = l_i[r] * alpha[r] + rs[r];

#pragma unroll
                    for (int n = 0; n < 4; ++n)
#pragma unroll
                        for (int r = 0; r < 4; ++r)
                            o[n][r] *= alpha[r];

                    bf16x8 pa0 = *(const bf16x8*)&ps[g * 16 * PSS + col * PSS + quad * 8];
                    bf16x8 pa1 = *(const bf16x8*)&ps[g * 16 * PSS + col * PSS + 32 + quad * 8];
#pragma unroll
                    for (int n = 0; n < 4; ++n) {
                        o[n] = __builtin_amdgcn_mfma_f32_16x16x32_bf16(pa0, vf[n * 2],     o[n], 0, 0, 0);
                        o[n] = __builtin_amdgcn_mfma_f32_16x16x32_bf16(pa1, vf[n * 2 + 1], o[n], 0, 0, 0);
                    }
                }

                // split-K combine (oc overlays ps)
                __syncthreads();
#pragma unroll
                for (int r = 0; r < 4; ++r) {
                    int row = quad * 4 + r;
#pragma unroll
                    for (int n = 0; n < 4; ++n)
                        oc[(g * 16 + row) * 68 + n * 16 + col] = o[n][r];
                }
                if (col == 0) {
#pragma unroll
                    for (int r = 0; r < 4; ++r) {
                        ml[(g * 2 + 0) * 16 + quad * 4 + r] = m_i[r];
                        ml[(g * 2 + 1) * 16 + quad * 4 + r] = l_i[r];
                    }
                }
                __syncthreads();

#pragma unroll
                for (int rr = 0; rr < 2; ++rr) {
                    int row = g * 2 + rr;
                    float M = ml[0 * 32 + row];
#pragma unroll
                    for (int j = 1; j < 8; ++j) M = fmaxf(M, ml[j * 32 + row]);
                    float lsum = 0.f, osum = 0.f;
#pragma unroll
                    for (int j = 0; j < 8; ++j) {
                        float wgt = __builtin_amdgcn_exp2f(ml[j * 32 + row] - M);
                        lsum += ml[j * 32 + 16 + row] * wgt;
                        osum += oc[(j * 16 + row) * 68 + lane] * wgt;
                    }
                    out[((long)b * T_ + qt * 16 + row) * H_ + lane] = osum / lsum;
                }
                __syncthreads();
            }
        }
    }
}

extern "C" void kernel_launch(void* const* d_in, const int* in_sizes, int n_in,
                              void* d_out, int out_size, void* d_ws, size_t ws_size,
                              hipStream_t stream) {
    (void)in_sizes; (void)n_in; (void)out_size; (void)ws_size;
    const float* x  = (const float*)d_in[0];
    const float* Wq = (const float*)d_in[1];
    const float* Wk = (const float*)d_in[2];
    const float* Wv = (const float*)d_in[3];

    unsigned short* qb  = (unsigned short*)d_ws;               // 2 MB
    unsigned short* kb  = qb + (size_t)BT_ * H_;               // 2 MB
    unsigned short* vtb = kb + (size_t)BT_ * H_;               // 2 MB
    unsigned short* wf  = vtb + (size_t)BT_ * H_;              // 384 KB
    unsigned*       bar = (unsigned*)(wf + (size_t)3 * H_ * E_);
    float*          out = (float*)d_out;

    hipMemsetAsync(bar, 0, 64, stream);    // zero barrier counters (graph-legal)
    fused_kernel<<<NBLK, 512, 0, stream>>>(x, Wq, Wk, Wv, qb, kb, vtb, wf, out, bar);
}